// Round 18
// baseline (35.377 us; speedup 1.0000x reference)
//
#include <hip/hip_runtime.h>

#define NN 128
#define DD 128
#define LL 512
#define FFH 512
#define TANH1 0.76159415595576489f

typedef __attribute__((ext_vector_type(8))) short bf16x8;
typedef __attribute__((ext_vector_type(4))) float f32x4;

struct alignas(16) f4arr { float v[4]; };

__device__ __forceinline__ unsigned short f2bf(float f) {
    union { float f; unsigned u; } v; v.f = f;
    return (unsigned short)((v.u + 0x7FFFu + ((v.u >> 16) & 1u)) >> 16);
}

// NaN-free fast tanh (validated R15): 1 - 2/(e^{2x}+1).
__device__ __forceinline__ float tanh_fast(float x) {
    const float e = __expf(2.f * x);
    return 1.f - 2.f / (e + 1.f);
}

// Gather one MFMA A-fragment (lane: m = col, k = ks*32 + l4*8 + je) from a
// row-major fp32 matrix W[k][m], leading dim ld (validated R15/R16; lanes
// cover 16 consecutive cols x 4 rows per load -> full line utilization).
__device__ __forceinline__ bf16x8 gather_frag(const float* __restrict__ W,
                                              int ld, int ks, int l4, int col) {
    float x[8];
    #pragma unroll
    for (int je = 0; je < 8; ++je)
        x[je] = W[(ks * 32 + l4 * 8 + je) * ld + col];
    union { bf16x8 v; unsigned u[4]; } r;
    #pragma unroll
    for (int i = 0; i < 4; ++i)
        r.u[i] = (unsigned)f2bf(x[2 * i]) | ((unsigned)f2bf(x[2 * i + 1]) << 16);
    return r.v;
}

// ---------------------------------------------------------------------------
// k_one: 32 blocks x 1024 thr (16 waves). Block = (b = blk>>1, half = blk&1,
// rows j0 = half*64 .. +63). Single kernel, no cross-block coupling:
//  S0 stage in_obs[b] -> LDS bf16 swizzled (R15)
//  S1 scores for WHOLE batch via MFMA + fused tanh*wv reduce (R15; 2x
//     redundancy total since both halves compute c[b,:])
//  S2 softmax in-reg  S3 attn  S4 LN1 (own 64 rows -> res in in_frag region)
//  S5 FF1 MFMA (gathered ff1 frags)  S6 FF2 MFMA (gathered ff2 frags)
//  S7 LN2 -> out
// ---------------------------------------------------------------------------
__global__ __launch_bounds__(1024, 1) void k_one(
    const float* __restrict__ in_obs,
    const float* __restrict__ Wk_w,
    const float* __restrict__ Wk_b,
    const float* __restrict__ wv_w,
    const float* __restrict__ ff1_w,
    const float* __restrict__ ff2_w,
    const float* __restrict__ g1, const float* __restrict__ b1,
    const float* __restrict__ ff1_b,
    const float* __restrict__ ff2_b,
    const float* __restrict__ g2, const float* __restrict__ b2,
    float* __restrict__ out)
{
    const int t = threadIdx.x;
    const int b = blockIdx.x >> 1;
    const int j0 = (blockIdx.x & 1) * 64;
    const int wave = t >> 6, lane = t & 63;
    const int l15 = lane & 15, l4 = lane >> 4;

    __shared__ alignas(16) unsigned short in_frag[128 * 128]; // 32 KB; rows 0..63 reused as res
    __shared__ alignas(16) unsigned short h_lds[64 * 512];    // 64 KB
    __shared__ alignas(16) float o2_lds[64 * 128];            // 32 KB
    __shared__ alignas(16) float part[16][128];               // 8 KB
    __shared__ float c_lds[128];
    __shared__ float attn_lds[128];

    // ================= S0: stage in_obs[b] -> swizzled bf16 ================
    {
        const int r = t >> 3;                 // row 0..127
        const int c0 = (t & 7) * 16;          // col group
        const float* src = in_obs + (b * NN + r) * DD + c0;
        const int swz = (r & 7) << 4;
        #pragma unroll
        for (int i = 0; i < 4; ++i) {
            const float4 v = *(const float4*)(src + i * 4);
            const unsigned p0 = (unsigned)f2bf(v.x) | ((unsigned)f2bf(v.y) << 16);
            const unsigned p1 = (unsigned)f2bf(v.z) | ((unsigned)f2bf(v.w) << 16);
            const int byte0 = (c0 + i * 4) * 2;
            *(unsigned*)((char*)in_frag + r * 256 + (byte0 ^ swz)) = p0;
            *(unsigned*)((char*)in_frag + r * 256 + ((byte0 + 4) ^ swz)) = p1;
        }
    }
    __syncthreads();

    // ================= S1: scores via MFMA (whole batch) ===================
    float cj[8];
    #pragma unroll
    for (int mt = 0; mt < 8; ++mt) cj[mt] = 0.f;
    {
        bf16x8 aW[2][4];
        #pragma unroll
        for (int ni = 0; ni < 2; ++ni) {
            const int ncol = (wave * 2 + ni) * 16 + l15;
            #pragma unroll
            for (int ks = 0; ks < 4; ++ks)
                aW[ni][ks] = gather_frag(Wk_w, LL, ks, l4, ncol);
        }
        #pragma unroll
        for (int mt = 0; mt < 8; ++mt) {
            const int row = mt * 16 + l15;
            bf16x8 bX[4];
            #pragma unroll
            for (int ks = 0; ks < 4; ++ks)
                bX[ks] = *(const bf16x8*)((const char*)in_frag + row * 256
                              + ((ks * 64 + l4 * 16) ^ ((row & 7) << 4)));
            #pragma unroll
            for (int ni = 0; ni < 2; ++ni) {
                f32x4 acc = {0.f, 0.f, 0.f, 0.f};
                #pragma unroll
                for (int ks = 0; ks < 4; ++ks)
                    acc = __builtin_amdgcn_mfma_f32_16x16x32_bf16(aW[ni][ks], bX[ks], acc, 0, 0, 0);
                const int lb = (wave * 2 + ni) * 16 + l4 * 4;
                const f4arr kb4 = *(const f4arr*)&Wk_b[lb];
                const f4arr wv4 = *(const f4arr*)&wv_w[640 + lb];
                #pragma unroll
                for (int r = 0; r < 4; ++r)
                    cj[mt] += tanh_fast(acc[r] + kb4.v[r]) * wv4.v[r];
            }
        }
    }
    #pragma unroll
    for (int mt = 0; mt < 8; ++mt) {
        cj[mt] += __shfl_xor(cj[mt], 16, 64);
        cj[mt] += __shfl_xor(cj[mt], 32, 64);
    }
    if (lane < 16) {
        #pragma unroll
        for (int mt = 0; mt < 8; ++mt)
            part[wave][mt * 16 + lane] = cj[mt];
    }
    __syncthreads();                           // A
    if (t < 128) {
        float cc = TANH1 * wv_w[1152 + t];
        #pragma unroll
        for (int g = 0; g < 16; ++g) cc += part[g][t];
        c_lds[t] = cc;
    }
    __syncthreads();                           // B

    // ================= S2: softmax in registers ============================
    const float cv0 = c_lds[lane];
    const float cv1 = c_lds[lane + 64];
    float mx = fmaxf(cv0, cv1);
    #pragma unroll
    for (int off = 32; off > 0; off >>= 1) mx = fmaxf(mx, __shfl_xor(mx, off, 64));
    float e0 = __expf(cv0 - mx), e1 = __expf(cv1 - mx);
    float sm = e0 + e1;
    #pragma unroll
    for (int off = 32; off > 0; off >>= 1) sm += __shfl_xor(sm, off, 64);
    const float inv = 1.f / sm;
    e0 *= inv; e1 *= inv;

    // ================= S3: attn partials (wave w: 8 j's) ===================
    {
        const float* base = in_obs + (b * NN + wave * 8) * DD;
        float a0 = 0.f, a1 = 0.f;
        #pragma unroll
        for (int jj = 0; jj < 8; ++jj) {
            const int js = wave * 8 + jj;
            const float wj = (wave < 8) ? __shfl(e0, js, 64)
                                        : __shfl(e1, js - 64, 64);
            a0 += wj * base[jj * DD + lane];
            a1 += wj * base[jj * DD + 64 + lane];
        }
        part[wave][lane] = a0;
        part[wave][lane + 64] = a1;
    }
    __syncthreads();                           // C
    if (t < 128) {
        float a = 0.f;
        #pragma unroll
        for (int g = 0; g < 16; ++g) a += part[g][t];
        attn_lds[t] = a;
    }
    __syncthreads();                           // D

    // ================= S4: LN1 own 64 rows -> res (in_frag region) =========
    #pragma unroll
    for (int rr = 0; rr < 4; ++rr) {
        const int rl = wave * 4 + rr;          // local row 0..63
        const int row = b * NN + j0 + rl;
        const int c0i = lane * 2;
        const float2 xo = *(const float2*)&in_obs[row * DD + c0i];
        const float x0 = attn_lds[c0i] + xo.x;
        const float x1 = attn_lds[c0i + 1] + xo.y;
        float s = x0 + x1;
        #pragma unroll
        for (int off = 32; off > 0; off >>= 1) s += __shfl_xor(s, off, 64);
        const float mu = s * (1.f / 128.f);
        const float d0 = x0 - mu, d1 = x1 - mu;
        float vs = d0 * d0 + d1 * d1;
        #pragma unroll
        for (int off = 32; off > 0; off >>= 1) vs += __shfl_xor(vs, off, 64);
        const float rstd = rsqrtf(vs * (1.f / 128.f) + 1e-5f);
        const float r0 = d0 * rstd * g1[c0i] + b1[c0i];
        const float r1 = d1 * rstd * g1[c0i + 1] + b1[c0i + 1];
        const unsigned pk = (unsigned)f2bf(r0) | ((unsigned)f2bf(r1) << 16);
        const int swz = (lane * 4) ^ ((rl & 7) << 4);
        *(unsigned*)((char*)in_frag + rl * 256 + swz) = pk;
    }
    __syncthreads();                           // E

    // ================= S5: FF1 (mt = wave*2 + {0,1}, rt = 0..3) ============
    {
        bf16x8 a1p[2][4];
        #pragma unroll
        for (int i = 0; i < 2; ++i) {
            const int mt = wave * 2 + i;
            #pragma unroll
            for (int ks = 0; ks < 4; ++ks)
                a1p[i][ks] = gather_frag(ff1_w, FFH, ks, l4, mt * 16 + l15);
        }
        #pragma unroll
        for (int rt = 0; rt < 4; ++rt) {
            const int rowl = rt * 16 + l15;
            bf16x8 bfrag[4];
            #pragma unroll
            for (int ks = 0; ks < 4; ++ks)
                bfrag[ks] = *(const bf16x8*)((const char*)in_frag + rowl * 256
                                + ((ks * 64 + l4 * 16) ^ ((rowl & 7) << 4)));
            #pragma unroll
            for (int i = 0; i < 2; ++i) {
                const int mt = wave * 2 + i;
                f32x4 acc = {0.f, 0.f, 0.f, 0.f};
                #pragma unroll
                for (int ks = 0; ks < 4; ++ks)
                    acc = __builtin_amdgcn_mfma_f32_16x16x32_bf16(a1p[i][ks], bfrag[ks], acc, 0, 0, 0);
                const f4arr bias = *(const f4arr*)&ff1_b[mt * 16 + l4 * 4];
                uint2 pk;
                pk.x = (unsigned)f2bf(fmaxf(acc[0] + bias.v[0], 0.f))
                     | ((unsigned)f2bf(fmaxf(acc[1] + bias.v[1], 0.f)) << 16);
                pk.y = (unsigned)f2bf(fmaxf(acc[2] + bias.v[2], 0.f))
                     | ((unsigned)f2bf(fmaxf(acc[3] + bias.v[3], 0.f)) << 16);
                const int off = rowl * 1024 + ((mt * 32 + l4 * 8) ^ ((rowl & 7) << 4));
                *(uint2*)((char*)h_lds + off) = pk;
            }
        }
    }
    __syncthreads();                           // F

    // ================= S6: FF2 (mt = wave&7, rt = (wave>>3)*2 + {0,1}) =====
    {
        const int mt = wave & 7;
        const int rtb = (wave >> 3) * 2;
        bf16x8 a2p[16];
        #pragma unroll
        for (int ks = 0; ks < 16; ++ks)
            a2p[ks] = gather_frag(ff2_w, DD, ks, l4, mt * 16 + l15);
        #pragma unroll
        for (int i2 = 0; i2 < 2; ++i2) {
            const int rt = rtb + i2;
            const int rowl = rt * 16 + l15;
            f32x4 acc = {0.f, 0.f, 0.f, 0.f};
            #pragma unroll
            for (int ks = 0; ks < 16; ++ks) {
                const bf16x8 bfrag = *(const bf16x8*)((const char*)h_lds + rowl * 1024
                                        + ((ks * 64 + l4 * 16) ^ ((rowl & 7) << 4)));
                acc = __builtin_amdgcn_mfma_f32_16x16x32_bf16(a2p[ks], bfrag, acc, 0, 0, 0);
            }
            const int off = rowl * 512 + ((mt * 64 + l4 * 16) ^ ((rowl & 7) << 4));
            *(f32x4*)((char*)o2_lds + off) = acc;
        }
    }
    __syncthreads();                           // G

    // ================= S7: LN2 own 64 rows -> out ==========================
    #pragma unroll
    for (int rr = 0; rr < 4; ++rr) {
        const int rl = wave * 4 + rr;
        const int row = b * NN + j0 + rl;
        const int c0i = lane * 2;
        const int off = rl * 512 + ((lane * 8) ^ ((rl & 7) << 4));
        const float2 o2 = *(const float2*)((char*)o2_lds + off);
        const float2 xo = *(const float2*)&in_obs[row * DD + c0i];
        const float f0 = o2.x + ff2_b[c0i] + xo.x;
        const float f1 = o2.y + ff2_b[c0i + 1] + xo.y;
        float s = f0 + f1;
        #pragma unroll
        for (int off2 = 32; off2 > 0; off2 >>= 1) s += __shfl_xor(s, off2, 64);
        const float mu = s * (1.f / 128.f);
        const float d0 = f0 - mu, d1 = f1 - mu;
        float vs = d0 * d0 + d1 * d1;
        #pragma unroll
        for (int off2 = 32; off2 > 0; off2 >>= 1) vs += __shfl_xor(vs, off2, 64);
        const float rstd = rsqrtf(vs * (1.f / 128.f) + 1e-5f);
        float2 o;
        o.x = d0 * rstd * g2[c0i]     + b2[c0i];
        o.y = d1 * rstd * g2[c0i + 1] + b2[c0i + 1];
        *(float2*)&out[row * DD + c0i] = o;
    }
}

extern "C" void kernel_launch(void* const* d_in, const int* in_sizes, int n_in,
                              void* d_out, int out_size, void* d_ws, size_t ws_size,
                              hipStream_t stream) {
    const float* in_obs = (const float*)d_in[0];
    // d_in[1] Wq_w, d_in[2] Wq_b, d_in[6] wv_b: dead (cancel in softmax)
    const float* Wk_w  = (const float*)d_in[3];
    const float* Wk_b  = (const float*)d_in[4];
    const float* wv_w  = (const float*)d_in[5];
    const float* g1    = (const float*)d_in[7];
    const float* b1    = (const float*)d_in[8];
    const float* ff1_w = (const float*)d_in[9];
    const float* ff1_b = (const float*)d_in[10];
    const float* ff2_w = (const float*)d_in[11];
    const float* ff2_b = (const float*)d_in[12];
    const float* g2    = (const float*)d_in[13];
    const float* b2    = (const float*)d_in[14];
    float* outp = (float*)d_out;

    k_one<<<32, 1024, 0, stream>>>(in_obs, Wk_w, Wk_b, wv_w, ff1_w, ff2_w,
                                   g1, b1, ff1_b, ff2_b, g2, b2, outp);
}